// Round 1
// baseline (729.034 us; speedup 1.0000x reference)
//
#include <hip/hip_runtime.h>
#include <stdint.h>

// ---------------------------------------------------------------------------
// 2-layer GCN: x = GCNConv(relu(GCNConv(X, W1,b1)), W2,b2)
// GCNConv(x): h = xW; out[d] = sum_{e:(s->d)} h[s]*dinv[s]*dinv[d]
//                     + h[d]*dinv[d]^2 + b
// dinv = 1/sqrt(in_degree + 1)
// Strategy: build dst-CSR once (int atomics only), gather-aggregate per node
// (no f32 atomics), f32 tiled SGEMM for xW (no fp32 MFMA on CDNA4).
// ---------------------------------------------------------------------------

__global__ void count_kernel(const int* __restrict__ dst, int* __restrict__ cnt, int E) {
    int e = blockIdx.x * blockDim.x + threadIdx.x;
    if (e < E) atomicAdd(&cnt[dst[e]], 1);
}

__global__ void dinv_kernel(const int* __restrict__ cnt, float* __restrict__ dinv, int n) {
    int i = blockIdx.x * blockDim.x + threadIdx.x;
    if (i < n) dinv[i] = 1.0f / sqrtf((float)cnt[i] + 1.0f);
}

// single-block exclusive scan of cnt[0..n) -> row_ptr / cursor
__global__ void scan_kernel(const int* __restrict__ cnt, int* __restrict__ row_ptr,
                            int* __restrict__ cursor, int n) {
    __shared__ int sdata[1024];
    __shared__ int carry_s;
    int tid = threadIdx.x;
    if (tid == 0) carry_s = 0;
    for (int base = 0; base < n; base += 1024) {
        int i = base + tid;
        int v = (i < n) ? cnt[i] : 0;
        __syncthreads();               // protect sdata reuse + carry init
        sdata[tid] = v;
        __syncthreads();
        for (int off = 1; off < 1024; off <<= 1) {
            int t = (tid >= off) ? sdata[tid - off] : 0;
            __syncthreads();
            sdata[tid] += t;
            __syncthreads();
        }
        int excl = sdata[tid] - v;     // exclusive within chunk
        int c0 = carry_s;
        if (i < n) { row_ptr[i] = c0 + excl; cursor[i] = c0 + excl; }
        __syncthreads();
        if (tid == 0) carry_s = c0 + sdata[1023];
    }
    __syncthreads();
    if (tid == 0) row_ptr[n] = carry_s;
}

__global__ void fill_kernel(const int* __restrict__ src, const int* __restrict__ dst,
                            int* __restrict__ cursor, int* __restrict__ csr_src, int E) {
    int e = blockIdx.x * blockDim.x + threadIdx.x;
    if (e < E) {
        int pos = atomicAdd(&cursor[dst[e]], 1);
        csr_src[pos] = src[e];
    }
}

// ---------------------------------------------------------------------------
// f32 SGEMM: C[M x 256] = A[M x 256] @ B[256 x 256]
// 64x64 tile, BK=32, 256 threads, 4x4 micro-tile per thread.
// As padded +4: k-stride 68 floats -> transposed scalar stores are 2-way
// (free), and (kk*272 + ty*16) keeps ds_read_b128 16B-aligned.
// ---------------------------------------------------------------------------
#define BM 64
#define BN 64
#define BK 32

__global__ __launch_bounds__(256) void sgemm_kernel(const float* __restrict__ A,
        const float* __restrict__ B, float* __restrict__ C, int M) {
    __shared__ float As[BK][BM + 4];
    __shared__ float Bs[BK][BN];
    const int tid = threadIdx.x;
    const int tx = tid & 15;
    const int ty = tid >> 4;
    const int row0 = blockIdx.x * BM;
    const int col0 = blockIdx.y * BN;
    float acc[4][4] = {};
    for (int k0 = 0; k0 < 256; k0 += BK) {
#pragma unroll
        for (int i = 0; i < 2; i++) {          // A tile: 64 rows x 32 cols
            int l = tid + i * 256;             // 512 float4 slots
            int r = l >> 3;
            int c4 = l & 7;
            int gr = row0 + r;
            float4 v = make_float4(0.f, 0.f, 0.f, 0.f);
            if (gr < M) v = *(const float4*)(A + (size_t)gr * 256 + k0 + c4 * 4);
            As[c4 * 4 + 0][r] = v.x;
            As[c4 * 4 + 1][r] = v.y;
            As[c4 * 4 + 2][r] = v.z;
            As[c4 * 4 + 3][r] = v.w;
        }
#pragma unroll
        for (int i = 0; i < 2; i++) {          // B tile: 32 rows x 64 cols
            int l = tid + i * 256;
            int r = l >> 4;
            int c4 = l & 15;
            *(float4*)&Bs[r][c4 * 4] =
                *(const float4*)(B + (size_t)(k0 + r) * 256 + col0 + c4 * 4);
        }
        __syncthreads();
#pragma unroll
        for (int kk = 0; kk < BK; kk++) {
            float a[4], b[4];
            *(float4*)a = *(const float4*)&As[kk][ty * 4];
            *(float4*)b = *(const float4*)&Bs[kk][tx * 4];
#pragma unroll
            for (int i = 0; i < 4; i++)
#pragma unroll
                for (int j = 0; j < 4; j++)
                    acc[i][j] += a[i] * b[j];
        }
        __syncthreads();
    }
#pragma unroll
    for (int i = 0; i < 4; i++) {
        int gr = row0 + ty * 4 + i;
        if (gr < M) *(float4*)(C + (size_t)gr * 256 + col0 + tx * 4) = *(float4*)acc[i];
    }
}

// ---------------------------------------------------------------------------
// Per-node aggregation + self-loop + bias (+relu). One wave per node,
// lane covers 4 cols via float4 (16B/lane coalesced gather of h rows).
// ---------------------------------------------------------------------------
__global__ __launch_bounds__(256) void agg_kernel(const float* __restrict__ h,
        const int* __restrict__ csr_src, const int* __restrict__ row_ptr,
        const float* __restrict__ dinv, const float* __restrict__ bias,
        float* __restrict__ out, int n, int do_relu) {
    int wid = threadIdx.x >> 6;
    int lane = threadIdx.x & 63;
    int node = blockIdx.x * 4 + wid;
    if (node >= n) return;
    float dn = dinv[node];
    int jb = row_ptr[node], je = row_ptr[node + 1];
    float4 acc = make_float4(0.f, 0.f, 0.f, 0.f);
    for (int j = jb; j < je; j++) {
        int s = csr_src[j];
        float w = dinv[s] * dn;
        float4 v = *(const float4*)(h + (size_t)s * 256 + lane * 4);
        acc.x += v.x * w; acc.y += v.y * w; acc.z += v.z * w; acc.w += v.w * w;
    }
    float4 hv = *(const float4*)(h + (size_t)node * 256 + lane * 4);
    float4 bv = *(const float4*)(bias + lane * 4);
    float s2 = dn * dn;
    float4 o;
    o.x = acc.x + hv.x * s2 + bv.x;
    o.y = acc.y + hv.y * s2 + bv.y;
    o.z = acc.z + hv.z * s2 + bv.z;
    o.w = acc.w + hv.w * s2 + bv.w;
    if (do_relu) {
        o.x = fmaxf(o.x, 0.f); o.y = fmaxf(o.y, 0.f);
        o.z = fmaxf(o.z, 0.f); o.w = fmaxf(o.w, 0.f);
    }
    *(float4*)(out + (size_t)node * 256 + lane * 4) = o;
}

extern "C" void kernel_launch(void* const* d_in, const int* in_sizes, int n_in,
                              void* d_out, int out_size, void* d_ws, size_t ws_size,
                              hipStream_t stream) {
    // inputs: 0 gene_ind_vec (unused), 1 edge_index, 2 embedding, 3 W1, 4 b1, 5 W2, 6 b2
    const int*   edge_index = (const int*)d_in[1];
    const float* embedding  = (const float*)d_in[2];
    const float* W1 = (const float*)d_in[3];
    const float* b1 = (const float*)d_in[4];
    const float* W2 = (const float*)d_in[5];
    const float* b2 = (const float*)d_in[6];
    float* out = (float*)d_out;

    const int E = in_sizes[1] / 2;
    const int n = in_sizes[2] / 256;
    const int* src = edge_index;
    const int* dst = edge_index + E;

    char* ws = (char*)d_ws;
    int* cnt = (int*)ws;        ws += ((size_t)n + 1) * 4;
    int* row_ptr = (int*)ws;    ws += ((size_t)n + 1) * 4;
    int* cursor = (int*)ws;     ws += (size_t)n * 4;
    float* dinv = (float*)ws;   ws += (size_t)n * 4;
    int* csr_src = (int*)ws;    ws += (size_t)E * 4;
    ws = (char*)(((uintptr_t)ws + 15) & ~(uintptr_t)15);
    float* h = (float*)ws;      // n*256 floats (51.2 MB)

    const int tb = 256;
    hipMemsetAsync(cnt, 0, (size_t)n * 4, stream);
    count_kernel<<<(E + tb - 1) / tb, tb, 0, stream>>>(dst, cnt, E);
    dinv_kernel<<<(n + tb - 1) / tb, tb, 0, stream>>>(cnt, dinv, n);
    scan_kernel<<<1, 1024, 0, stream>>>(cnt, row_ptr, cursor, n);
    fill_kernel<<<(E + tb - 1) / tb, tb, 0, stream>>>(src, dst, cursor, csr_src, E);

    dim3 ggrid((n + BM - 1) / BM, 256 / BN);
    // layer 1: h1 = X@W1 ; x1 = relu(agg(h1)+self+b1) -> d_out (scratch use)
    sgemm_kernel<<<ggrid, 256, 0, stream>>>(embedding, W1, h, n);
    agg_kernel<<<(n + 3) / 4, 256, 0, stream>>>(h, csr_src, row_ptr, dinv, b1, out, n, 1);
    // layer 2: h2 = x1@W2 ; out = agg(h2)+self+b2 -> d_out (final)
    sgemm_kernel<<<ggrid, 256, 0, stream>>>(out, W2, h, n);
    agg_kernel<<<(n + 3) / 4, 256, 0, stream>>>(h, csr_src, row_ptr, dinv, b2, out, n, 0);
}

// Round 2
// 671.730 us; speedup vs baseline: 1.0853x; 1.0853x over previous
//
#include <hip/hip_runtime.h>
#include <stdint.h>

// ---------------------------------------------------------------------------
// 2-layer GCN. Reformulation: g = (xW) row-scaled by dinv (fused in GEMM
// epilogue); out[d] = dinv[d] * (sum_{s in N(d)} g[s] + g[d]) + b.
// -> agg inner loop is a pure gather-add (no per-edge weights).
// ---------------------------------------------------------------------------

__global__ void count_kernel(const int* __restrict__ dst, int* __restrict__ cnt, int E) {
    int e = blockIdx.x * blockDim.x + threadIdx.x;
    if (e < E) atomicAdd(&cnt[dst[e]], 1);
}

__global__ void dinv_kernel(const int* __restrict__ cnt, float* __restrict__ dinv, int n) {
    int i = blockIdx.x * blockDim.x + threadIdx.x;
    if (i < n) dinv[i] = 1.0f / sqrtf((float)cnt[i] + 1.0f);
}

// hierarchical scan: per-1024-chunk exclusive scan + chunk totals
__global__ __launch_bounds__(1024) void scan_block(const int* __restrict__ cnt,
        int* __restrict__ row_ptr, int* __restrict__ bsum, int n) {
    __shared__ int sd[1024];
    int tid = threadIdx.x;
    int i = blockIdx.x * 1024 + tid;
    int v = (i < n) ? cnt[i] : 0;
    sd[tid] = v;
    __syncthreads();
    for (int off = 1; off < 1024; off <<= 1) {
        int t = (tid >= off) ? sd[tid - off] : 0;
        __syncthreads();
        sd[tid] += t;
        __syncthreads();
    }
    if (i < n) row_ptr[i] = sd[tid] - v;   // exclusive within chunk
    if (tid == 1023) bsum[blockIdx.x] = sd[1023];
}

__global__ __launch_bounds__(1024) void scan_bsum(int* __restrict__ bsum, int nb) {
    __shared__ int sd[1024];
    int tid = threadIdx.x;
    int v = (tid < nb) ? bsum[tid] : 0;
    sd[tid] = v;
    __syncthreads();
    for (int off = 1; off < 1024; off <<= 1) {
        int t = (tid >= off) ? sd[tid - off] : 0;
        __syncthreads();
        sd[tid] += t;
        __syncthreads();
    }
    if (tid < nb) bsum[tid] = sd[tid] - v; // exclusive
}

__global__ void scan_add(int* __restrict__ row_ptr, int* __restrict__ cursor,
                         const int* __restrict__ bsum, int n, int E) {
    int i = blockIdx.x * blockDim.x + threadIdx.x;
    if (i < n) {
        int r = row_ptr[i] + bsum[i >> 10];
        row_ptr[i] = r;
        cursor[i] = r;
    }
    if (i == n) row_ptr[n] = E;
}

__global__ void fill_kernel(const int* __restrict__ src, const int* __restrict__ dst,
                            int* __restrict__ cursor, int* __restrict__ csr_src, int E) {
    int e = blockIdx.x * blockDim.x + threadIdx.x;
    if (e < E) {
        int pos = atomicAdd(&cursor[dst[e]], 1);
        csr_src[pos] = src[e];
    }
}

// ---------------------------------------------------------------------------
// f32 SGEMM, C[M x 256] = A[M x 256] @ B[256 x 256], epilogue row-scale by
// dinv. 128x128 tile, BK=32, 256 threads, 8x8 micro-tile as 2x2 quadrants of
// 4x4 (16B-stride LDS reads -> 2-way conflicts = free; A reads broadcast).
// ---------------------------------------------------------------------------
#define BM 128
#define BN 128
#define BK 32

__global__ __launch_bounds__(256) void sgemm_kernel(const float* __restrict__ A,
        const float* __restrict__ B, const float* __restrict__ dinv,
        float* __restrict__ C, int M) {
    __shared__ float As[BK][BM + 4];
    __shared__ float Bs[BK][BN];
    const int tid = threadIdx.x;
    const int tx = tid & 15;
    const int ty = tid >> 4;            // 0..15
    const int row0 = blockIdx.x * BM;
    const int col0 = blockIdx.y * BN;
    float acc[2][2][4][4] = {};         // [rowHalf][colHalf][i][j]
    for (int k0 = 0; k0 < 256; k0 += BK) {
#pragma unroll
        for (int i = 0; i < 4; i++) {   // A tile: 128 rows x 32 cols, transposed store
            int l = tid + i * 256;      // 0..1023 float4 slots
            int r = l >> 3;
            int c4 = l & 7;
            int gr = row0 + r;
            float4 v = make_float4(0.f, 0.f, 0.f, 0.f);
            if (gr < M) v = *(const float4*)(A + (size_t)gr * 256 + k0 + c4 * 4);
            As[c4 * 4 + 0][r] = v.x;
            As[c4 * 4 + 1][r] = v.y;
            As[c4 * 4 + 2][r] = v.z;
            As[c4 * 4 + 3][r] = v.w;
        }
#pragma unroll
        for (int i = 0; i < 4; i++) {   // B tile: 32 rows x 128 cols
            int l = tid + i * 256;
            int r = l >> 5;
            int c4 = l & 31;
            *(float4*)&Bs[r][c4 * 4] =
                *(const float4*)(B + (size_t)(k0 + r) * 256 + col0 + c4 * 4);
        }
        __syncthreads();
#pragma unroll
        for (int kk = 0; kk < BK; kk++) {
            float a[2][4], b[2][4];
            *(float4*)a[0] = *(const float4*)&As[kk][ty * 4];
            *(float4*)a[1] = *(const float4*)&As[kk][64 + ty * 4];
            *(float4*)b[0] = *(const float4*)&Bs[kk][tx * 4];
            *(float4*)b[1] = *(const float4*)&Bs[kk][64 + tx * 4];
#pragma unroll
            for (int p = 0; p < 2; p++)
#pragma unroll
                for (int q = 0; q < 2; q++)
#pragma unroll
                    for (int i = 0; i < 4; i++)
#pragma unroll
                        for (int j = 0; j < 4; j++)
                            acc[p][q][i][j] += a[p][i] * b[q][j];
        }
        __syncthreads();
    }
#pragma unroll
    for (int p = 0; p < 2; p++)
#pragma unroll
        for (int i = 0; i < 4; i++) {
            int gr = row0 + p * 64 + ty * 4 + i;
            if (gr < M) {
                float s = dinv[gr];
                float4 o;
                o.x = acc[p][0][i][0] * s; o.y = acc[p][0][i][1] * s;
                o.z = acc[p][0][i][2] * s; o.w = acc[p][0][i][3] * s;
                *(float4*)(C + (size_t)gr * 256 + col0 + tx * 4) = o;
                o.x = acc[p][1][i][0] * s; o.y = acc[p][1][i][1] * s;
                o.z = acc[p][1][i][2] * s; o.w = acc[p][1][i][3] * s;
                *(float4*)(C + (size_t)gr * 256 + col0 + 64 + tx * 4) = o;
            }
        }
}

// ---------------------------------------------------------------------------
// Aggregation: one wave per node, lane = 4 cols (float4). Pure gather-add of
// g rows, unrolled x8 for 8 outstanding gathers per wave. Epilogue scales by
// dinv[node] once, adds bias, optional relu.
// ---------------------------------------------------------------------------
__global__ __launch_bounds__(256) void agg_kernel(const float* __restrict__ g,
        const int* __restrict__ csr_src, const int* __restrict__ row_ptr,
        const float* __restrict__ dinv, const float* __restrict__ bias,
        float* __restrict__ out, int n, int do_relu) {
    int wid = threadIdx.x >> 6;
    int lane = threadIdx.x & 63;
    int node = blockIdx.x * 4 + wid;
    if (node >= n) return;
    int jb = row_ptr[node], je = row_ptr[node + 1];
    const size_t co = (size_t)(lane * 4);
    float4 a0 = make_float4(0.f, 0.f, 0.f, 0.f);
    float4 a1 = make_float4(0.f, 0.f, 0.f, 0.f);
    int j = jb;
    for (; j + 8 <= je; j += 8) {
        int s0 = csr_src[j + 0], s1 = csr_src[j + 1];
        int s2 = csr_src[j + 2], s3 = csr_src[j + 3];
        int s4 = csr_src[j + 4], s5 = csr_src[j + 5];
        int s6 = csr_src[j + 6], s7 = csr_src[j + 7];
        float4 v0 = *(const float4*)(g + ((size_t)s0 << 8) + co);
        float4 v1 = *(const float4*)(g + ((size_t)s1 << 8) + co);
        float4 v2 = *(const float4*)(g + ((size_t)s2 << 8) + co);
        float4 v3 = *(const float4*)(g + ((size_t)s3 << 8) + co);
        float4 v4 = *(const float4*)(g + ((size_t)s4 << 8) + co);
        float4 v5 = *(const float4*)(g + ((size_t)s5 << 8) + co);
        float4 v6 = *(const float4*)(g + ((size_t)s6 << 8) + co);
        float4 v7 = *(const float4*)(g + ((size_t)s7 << 8) + co);
        a0.x += v0.x; a0.y += v0.y; a0.z += v0.z; a0.w += v0.w;
        a1.x += v1.x; a1.y += v1.y; a1.z += v1.z; a1.w += v1.w;
        a0.x += v2.x; a0.y += v2.y; a0.z += v2.z; a0.w += v2.w;
        a1.x += v3.x; a1.y += v3.y; a1.z += v3.z; a1.w += v3.w;
        a0.x += v4.x; a0.y += v4.y; a0.z += v4.z; a0.w += v4.w;
        a1.x += v5.x; a1.y += v5.y; a1.z += v5.z; a1.w += v5.w;
        a0.x += v6.x; a0.y += v6.y; a0.z += v6.z; a0.w += v6.w;
        a1.x += v7.x; a1.y += v7.y; a1.z += v7.z; a1.w += v7.w;
    }
    for (; j < je; ++j) {
        int s = csr_src[j];
        float4 v = *(const float4*)(g + ((size_t)s << 8) + co);
        a0.x += v.x; a0.y += v.y; a0.z += v.z; a0.w += v.w;
    }
    float4 gd = *(const float4*)(g + ((size_t)node << 8) + co);
    float dn = dinv[node];
    float4 bv = *(const float4*)(bias + co);
    float4 o;
    o.x = (a0.x + a1.x + gd.x) * dn + bv.x;
    o.y = (a0.y + a1.y + gd.y) * dn + bv.y;
    o.z = (a0.z + a1.z + gd.z) * dn + bv.z;
    o.w = (a0.w + a1.w + gd.w) * dn + bv.w;
    if (do_relu) {
        o.x = fmaxf(o.x, 0.f); o.y = fmaxf(o.y, 0.f);
        o.z = fmaxf(o.z, 0.f); o.w = fmaxf(o.w, 0.f);
    }
    *(float4*)(out + ((size_t)node << 8) + co) = o;
}

extern "C" void kernel_launch(void* const* d_in, const int* in_sizes, int n_in,
                              void* d_out, int out_size, void* d_ws, size_t ws_size,
                              hipStream_t stream) {
    // inputs: 0 gene_ind_vec (unused), 1 edge_index, 2 embedding, 3 W1, 4 b1, 5 W2, 6 b2
    const int*   edge_index = (const int*)d_in[1];
    const float* embedding  = (const float*)d_in[2];
    const float* W1 = (const float*)d_in[3];
    const float* b1 = (const float*)d_in[4];
    const float* W2 = (const float*)d_in[5];
    const float* b2 = (const float*)d_in[6];
    float* out = (float*)d_out;

    const int E = in_sizes[1] / 2;
    const int n = in_sizes[2] / 256;
    const int* src = edge_index;
    const int* dst = edge_index + E;

    char* ws = (char*)d_ws;
    int* cnt = (int*)ws;        ws += (size_t)n * 4;      // reused as cursor
    int* row_ptr = (int*)ws;    ws += ((size_t)n + 1) * 4;
    float* dinv = (float*)ws;   ws += (size_t)n * 4;
    int* bsum = (int*)ws;       ws += 1024 * 4;
    int* csr_src = (int*)ws;    ws += (size_t)E * 4;
    ws = (char*)(((uintptr_t)ws + 15) & ~(uintptr_t)15);
    float* h = (float*)ws;      // n*256 floats

    const int tb = 256;
    const int nchunks = (n + 1023) / 1024;
    hipMemsetAsync(cnt, 0, (size_t)n * 4, stream);
    count_kernel<<<(E + tb - 1) / tb, tb, 0, stream>>>(dst, cnt, E);
    dinv_kernel<<<(n + tb - 1) / tb, tb, 0, stream>>>(cnt, dinv, n);
    scan_block<<<nchunks, 1024, 0, stream>>>(cnt, row_ptr, bsum, n);
    scan_bsum<<<1, 1024, 0, stream>>>(bsum, nchunks);
    scan_add<<<(n + tb) / tb, tb, 0, stream>>>(row_ptr, cnt, bsum, n, E);
    fill_kernel<<<(E + tb - 1) / tb, tb, 0, stream>>>(src, dst, cnt, csr_src, E);

    dim3 ggrid((n + BM - 1) / BM, 256 / BN);
    // layer 1: g1 = (X@W1) * dinv[row]; x1 = relu(dinv*(agg+self)+b1) -> d_out
    sgemm_kernel<<<ggrid, 256, 0, stream>>>(embedding, W1, dinv, h, n);
    agg_kernel<<<(n + 3) / 4, 256, 0, stream>>>(h, csr_src, row_ptr, dinv, b1, out, n, 1);
    // layer 2: g2 = (x1@W2) * dinv[row]; out = dinv*(agg+self)+b2
    sgemm_kernel<<<ggrid, 256, 0, stream>>>(out, W2, dinv, h, n);
    agg_kernel<<<(n + 3) / 4, 256, 0, stream>>>(h, csr_src, row_ptr, dinv, b2, out, n, 0);
}

// Round 3
// 493.347 us; speedup vs baseline: 1.4777x; 1.3616x over previous
//
#include <hip/hip_runtime.h>
#include <stdint.h>

// ---------------------------------------------------------------------------
// 2-layer GCN. g = (xW) row-scaled by dinv, stored BF16 (halves gather bytes;
// agg is gather-byte-throughput-bound per R1/R2 counters).
// out[d] = dinv[d] * (sum_{s in N(d)} g[s] + g[d]) + b, accumulated in f32.
// ---------------------------------------------------------------------------

typedef unsigned short u16;

__device__ __forceinline__ float bf2f(u16 u) {
    union { unsigned i; float f; } c;
    c.i = ((unsigned)u) << 16;
    return c.f;
}
__device__ __forceinline__ u16 f2bf(float f) {
    union { float f; unsigned i; } c;
    c.f = f;
    unsigned i = c.i;
    return (u16)((i + 0x7FFF + ((i >> 16) & 1)) >> 16);   // RNE
}

__global__ void count_kernel(const int* __restrict__ dst, int* __restrict__ cnt, int E) {
    int e = blockIdx.x * blockDim.x + threadIdx.x;
    if (e < E) atomicAdd(&cnt[dst[e]], 1);
}

__global__ void dinv_kernel(const int* __restrict__ cnt, float* __restrict__ dinv, int n) {
    int i = blockIdx.x * blockDim.x + threadIdx.x;
    if (i < n) dinv[i] = 1.0f / sqrtf((float)cnt[i] + 1.0f);
}

// hierarchical scan: per-1024-chunk exclusive scan + chunk totals
__global__ __launch_bounds__(1024) void scan_block(const int* __restrict__ cnt,
        int* __restrict__ row_ptr, int* __restrict__ bsum, int n) {
    __shared__ int sd[1024];
    int tid = threadIdx.x;
    int i = blockIdx.x * 1024 + tid;
    int v = (i < n) ? cnt[i] : 0;
    sd[tid] = v;
    __syncthreads();
    for (int off = 1; off < 1024; off <<= 1) {
        int t = (tid >= off) ? sd[tid - off] : 0;
        __syncthreads();
        sd[tid] += t;
        __syncthreads();
    }
    if (i < n) row_ptr[i] = sd[tid] - v;   // exclusive within chunk
    if (tid == 1023) bsum[blockIdx.x] = sd[1023];
}

__global__ __launch_bounds__(1024) void scan_bsum(int* __restrict__ bsum, int nb) {
    __shared__ int sd[1024];
    int tid = threadIdx.x;
    int v = (tid < nb) ? bsum[tid] : 0;
    sd[tid] = v;
    __syncthreads();
    for (int off = 1; off < 1024; off <<= 1) {
        int t = (tid >= off) ? sd[tid - off] : 0;
        __syncthreads();
        sd[tid] += t;
        __syncthreads();
    }
    if (tid < nb) bsum[tid] = sd[tid] - v; // exclusive
}

__global__ void scan_add(int* __restrict__ row_ptr, int* __restrict__ cursor,
                         const int* __restrict__ bsum, int n, int E) {
    int i = blockIdx.x * blockDim.x + threadIdx.x;
    if (i < n) {
        int r = row_ptr[i] + bsum[i >> 10];
        row_ptr[i] = r;
        cursor[i] = r;
    }
    if (i == n) row_ptr[n] = E;
}

__global__ void fill_kernel(const int* __restrict__ src, const int* __restrict__ dst,
                            int* __restrict__ cursor, int* __restrict__ csr_src, int E) {
    int e = blockIdx.x * blockDim.x + threadIdx.x;
    if (e < E) {
        int pos = atomicAdd(&cursor[dst[e]], 1);
        csr_src[pos] = src[e];
    }
}

// ---------------------------------------------------------------------------
// f32 SGEMM, C[M x 256] = A[M x 256] @ B[256 x 256]; epilogue scales row by
// dinv and stores BF16. 128x128 tile, BK=32, 256 threads, 8x8 micro-tile.
// ---------------------------------------------------------------------------
#define BM 128
#define BN 128
#define BK 32

__global__ __launch_bounds__(256) void sgemm_kernel(const float* __restrict__ A,
        const float* __restrict__ B, const float* __restrict__ dinv,
        u16* __restrict__ C, int M) {
    __shared__ float As[BK][BM + 4];
    __shared__ float Bs[BK][BN];
    const int tid = threadIdx.x;
    const int tx = tid & 15;
    const int ty = tid >> 4;            // 0..15
    const int row0 = blockIdx.x * BM;
    const int col0 = blockIdx.y * BN;
    float acc[2][2][4][4] = {};         // [rowHalf][colHalf][i][j]
    for (int k0 = 0; k0 < 256; k0 += BK) {
#pragma unroll
        for (int i = 0; i < 4; i++) {   // A tile: 128 rows x 32 cols, transposed store
            int l = tid + i * 256;      // 0..1023 float4 slots
            int r = l >> 3;
            int c4 = l & 7;
            int gr = row0 + r;
            float4 v = make_float4(0.f, 0.f, 0.f, 0.f);
            if (gr < M) v = *(const float4*)(A + (size_t)gr * 256 + k0 + c4 * 4);
            As[c4 * 4 + 0][r] = v.x;
            As[c4 * 4 + 1][r] = v.y;
            As[c4 * 4 + 2][r] = v.z;
            As[c4 * 4 + 3][r] = v.w;
        }
#pragma unroll
        for (int i = 0; i < 4; i++) {   // B tile: 32 rows x 128 cols
            int l = tid + i * 256;
            int r = l >> 5;
            int c4 = l & 31;
            *(float4*)&Bs[r][c4 * 4] =
                *(const float4*)(B + (size_t)(k0 + r) * 256 + col0 + c4 * 4);
        }
        __syncthreads();
#pragma unroll
        for (int kk = 0; kk < BK; kk++) {
            float a[2][4], b[2][4];
            *(float4*)a[0] = *(const float4*)&As[kk][ty * 4];
            *(float4*)a[1] = *(const float4*)&As[kk][64 + ty * 4];
            *(float4*)b[0] = *(const float4*)&Bs[kk][tx * 4];
            *(float4*)b[1] = *(const float4*)&Bs[kk][64 + tx * 4];
#pragma unroll
            for (int p = 0; p < 2; p++)
#pragma unroll
                for (int q = 0; q < 2; q++)
#pragma unroll
                    for (int i = 0; i < 4; i++)
#pragma unroll
                        for (int j = 0; j < 4; j++)
                            acc[p][q][i][j] += a[p][i] * b[q][j];
        }
        __syncthreads();
    }
#pragma unroll
    for (int p = 0; p < 2; p++)
#pragma unroll
        for (int i = 0; i < 4; i++) {
            int gr = row0 + p * 64 + ty * 4 + i;
            if (gr < M) {
                float s = dinv[gr];
                ushort4 o;
                o.x = f2bf(acc[p][0][i][0] * s); o.y = f2bf(acc[p][0][i][1] * s);
                o.z = f2bf(acc[p][0][i][2] * s); o.w = f2bf(acc[p][0][i][3] * s);
                *(ushort4*)(C + (size_t)gr * 256 + col0 + tx * 4) = o;
                o.x = f2bf(acc[p][1][i][0] * s); o.y = f2bf(acc[p][1][i][1] * s);
                o.z = f2bf(acc[p][1][i][2] * s); o.w = f2bf(acc[p][1][i][3] * s);
                *(ushort4*)(C + (size_t)gr * 256 + col0 + 64 + tx * 4) = o;
            }
        }
}

// ---------------------------------------------------------------------------
// Aggregation: one wave per node, lane = 4 cols (ushort4 bf16 gather, 8B/lane,
// 512B/edge). f32 accumulate, unrolled x8 for MLP. Epilogue: scale by
// dinv[node], add bias, optional relu; f32 output.
// ---------------------------------------------------------------------------
__global__ __launch_bounds__(256) void agg_kernel(const u16* __restrict__ g,
        const int* __restrict__ csr_src, const int* __restrict__ row_ptr,
        const float* __restrict__ dinv, const float* __restrict__ bias,
        float* __restrict__ out, int n, int do_relu) {
    int wid = threadIdx.x >> 6;
    int lane = threadIdx.x & 63;
    int node = blockIdx.x * 4 + wid;
    if (node >= n) return;
    int jb = row_ptr[node], je = row_ptr[node + 1];
    const size_t co = (size_t)(lane * 4);
    float4 a0 = make_float4(0.f, 0.f, 0.f, 0.f);
    float4 a1 = make_float4(0.f, 0.f, 0.f, 0.f);
    int j = jb;
    for (; j + 8 <= je; j += 8) {
        int s0 = csr_src[j + 0], s1 = csr_src[j + 1];
        int s2 = csr_src[j + 2], s3 = csr_src[j + 3];
        int s4 = csr_src[j + 4], s5 = csr_src[j + 5];
        int s6 = csr_src[j + 6], s7 = csr_src[j + 7];
        ushort4 v0 = *(const ushort4*)(g + ((size_t)s0 << 8) + co);
        ushort4 v1 = *(const ushort4*)(g + ((size_t)s1 << 8) + co);
        ushort4 v2 = *(const ushort4*)(g + ((size_t)s2 << 8) + co);
        ushort4 v3 = *(const ushort4*)(g + ((size_t)s3 << 8) + co);
        ushort4 v4 = *(const ushort4*)(g + ((size_t)s4 << 8) + co);
        ushort4 v5 = *(const ushort4*)(g + ((size_t)s5 << 8) + co);
        ushort4 v6 = *(const ushort4*)(g + ((size_t)s6 << 8) + co);
        ushort4 v7 = *(const ushort4*)(g + ((size_t)s7 << 8) + co);
        a0.x += bf2f(v0.x); a0.y += bf2f(v0.y); a0.z += bf2f(v0.z); a0.w += bf2f(v0.w);
        a1.x += bf2f(v1.x); a1.y += bf2f(v1.y); a1.z += bf2f(v1.z); a1.w += bf2f(v1.w);
        a0.x += bf2f(v2.x); a0.y += bf2f(v2.y); a0.z += bf2f(v2.z); a0.w += bf2f(v2.w);
        a1.x += bf2f(v3.x); a1.y += bf2f(v3.y); a1.z += bf2f(v3.z); a1.w += bf2f(v3.w);
        a0.x += bf2f(v4.x); a0.y += bf2f(v4.y); a0.z += bf2f(v4.z); a0.w += bf2f(v4.w);
        a1.x += bf2f(v5.x); a1.y += bf2f(v5.y); a1.z += bf2f(v5.z); a1.w += bf2f(v5.w);
        a0.x += bf2f(v6.x); a0.y += bf2f(v6.y); a0.z += bf2f(v6.z); a0.w += bf2f(v6.w);
        a1.x += bf2f(v7.x); a1.y += bf2f(v7.y); a1.z += bf2f(v7.z); a1.w += bf2f(v7.w);
    }
    for (; j < je; ++j) {
        int s = csr_src[j];
        ushort4 v = *(const ushort4*)(g + ((size_t)s << 8) + co);
        a0.x += bf2f(v.x); a0.y += bf2f(v.y); a0.z += bf2f(v.z); a0.w += bf2f(v.w);
    }
    ushort4 gd = *(const ushort4*)(g + ((size_t)node << 8) + co);
    float dn = dinv[node];
    float4 bv = *(const float4*)(bias + co);
    float4 o;
    o.x = (a0.x + a1.x + bf2f(gd.x)) * dn + bv.x;
    o.y = (a0.y + a1.y + bf2f(gd.y)) * dn + bv.y;
    o.z = (a0.z + a1.z + bf2f(gd.z)) * dn + bv.z;
    o.w = (a0.w + a1.w + bf2f(gd.w)) * dn + bv.w;
    if (do_relu) {
        o.x = fmaxf(o.x, 0.f); o.y = fmaxf(o.y, 0.f);
        o.z = fmaxf(o.z, 0.f); o.w = fmaxf(o.w, 0.f);
    }
    *(float4*)(out + ((size_t)node << 8) + co) = o;
}

extern "C" void kernel_launch(void* const* d_in, const int* in_sizes, int n_in,
                              void* d_out, int out_size, void* d_ws, size_t ws_size,
                              hipStream_t stream) {
    // inputs: 0 gene_ind_vec (unused), 1 edge_index, 2 embedding, 3 W1, 4 b1, 5 W2, 6 b2
    const int*   edge_index = (const int*)d_in[1];
    const float* embedding  = (const float*)d_in[2];
    const float* W1 = (const float*)d_in[3];
    const float* b1 = (const float*)d_in[4];
    const float* W2 = (const float*)d_in[5];
    const float* b2 = (const float*)d_in[6];
    float* out = (float*)d_out;

    const int E = in_sizes[1] / 2;
    const int n = in_sizes[2] / 256;
    const int* src = edge_index;
    const int* dst = edge_index + E;

    char* ws = (char*)d_ws;
    int* cnt = (int*)ws;        ws += (size_t)n * 4;      // reused as cursor
    int* row_ptr = (int*)ws;    ws += ((size_t)n + 1) * 4;
    float* dinv = (float*)ws;   ws += (size_t)n * 4;
    int* bsum = (int*)ws;       ws += 1024 * 4;
    int* csr_src = (int*)ws;    ws += (size_t)E * 4;
    ws = (char*)(((uintptr_t)ws + 127) & ~(uintptr_t)127);
    u16* g = (u16*)ws;          // n*256 bf16 (25.6 MB)

    const int tb = 256;
    const int nchunks = (n + 1023) / 1024;
    hipMemsetAsync(cnt, 0, (size_t)n * 4, stream);
    count_kernel<<<(E + tb - 1) / tb, tb, 0, stream>>>(dst, cnt, E);
    dinv_kernel<<<(n + tb - 1) / tb, tb, 0, stream>>>(cnt, dinv, n);
    scan_block<<<nchunks, 1024, 0, stream>>>(cnt, row_ptr, bsum, n);
    scan_bsum<<<1, 1024, 0, stream>>>(bsum, nchunks);
    scan_add<<<(n + tb) / tb, tb, 0, stream>>>(row_ptr, cnt, bsum, n, E);
    fill_kernel<<<(E + tb - 1) / tb, tb, 0, stream>>>(src, dst, cnt, csr_src, E);

    dim3 ggrid((n + BM - 1) / BM, 256 / BN);
    // layer 1: g1 = bf16(dinv*(X@W1)); x1 = relu(dinv*(agg+self)+b1) -> d_out
    sgemm_kernel<<<ggrid, 256, 0, stream>>>(embedding, W1, dinv, g, n);
    agg_kernel<<<(n + 3) / 4, 256, 0, stream>>>(g, csr_src, row_ptr, dinv, b1, out, n, 1);
    // layer 2: g2 = bf16(dinv*(x1@W2)); out = dinv*(agg+self)+b2
    sgemm_kernel<<<ggrid, 256, 0, stream>>>(out, W2, dinv, g, n);
    agg_kernel<<<(n + 3) / 4, 256, 0, stream>>>(g, csr_src, row_ptr, dinv, b2, out, n, 0);
}

// Round 4
// 347.511 us; speedup vs baseline: 2.0979x; 1.4197x over previous
//
#include <hip/hip_runtime.h>
#include <stdint.h>

// ---------------------------------------------------------------------------
// 2-layer GCN. g = (xW) row-scaled by dinv, stored BF16.
// out[d] = dinv[d] * (sum_{s in N(d)} g[s] + g[d]) + b, f32 accumulate.
// R4: xW via bf16 MFMA (16x16x32), f32 accumulate. W pre-transposed to bf16.
// ---------------------------------------------------------------------------

typedef unsigned short u16;
typedef __bf16 bf16x8 __attribute__((ext_vector_type(8)));
typedef float f32x4 __attribute__((ext_vector_type(4)));
typedef unsigned short us8 __attribute__((ext_vector_type(8)));
typedef unsigned short us4 __attribute__((ext_vector_type(4)));

__device__ __forceinline__ float bf2f(u16 u) {
    union { unsigned i; float f; } c;
    c.i = ((unsigned)u) << 16;
    return c.f;
}
__device__ __forceinline__ u16 f2bf(float f) {
    union { float f; unsigned i; } c;
    c.f = f;
    unsigned i = c.i;
    return (u16)((i + 0x7FFF + ((i >> 16) & 1)) >> 16);   // RNE
}

__global__ void count_kernel(const int* __restrict__ dst, int* __restrict__ cnt, int E) {
    int e = blockIdx.x * blockDim.x + threadIdx.x;
    if (e < E) atomicAdd(&cnt[dst[e]], 1);
}

__global__ void dinv_kernel(const int* __restrict__ cnt, float* __restrict__ dinv, int n) {
    int i = blockIdx.x * blockDim.x + threadIdx.x;
    if (i < n) dinv[i] = 1.0f / sqrtf((float)cnt[i] + 1.0f);
}

__global__ __launch_bounds__(1024) void scan_block(const int* __restrict__ cnt,
        int* __restrict__ row_ptr, int* __restrict__ bsum, int n) {
    __shared__ int sd[1024];
    int tid = threadIdx.x;
    int i = blockIdx.x * 1024 + tid;
    int v = (i < n) ? cnt[i] : 0;
    sd[tid] = v;
    __syncthreads();
    for (int off = 1; off < 1024; off <<= 1) {
        int t = (tid >= off) ? sd[tid - off] : 0;
        __syncthreads();
        sd[tid] += t;
        __syncthreads();
    }
    if (i < n) row_ptr[i] = sd[tid] - v;
    if (tid == 1023) bsum[blockIdx.x] = sd[1023];
}

__global__ __launch_bounds__(1024) void scan_bsum(int* __restrict__ bsum, int nb) {
    __shared__ int sd[1024];
    int tid = threadIdx.x;
    int v = (tid < nb) ? bsum[tid] : 0;
    sd[tid] = v;
    __syncthreads();
    for (int off = 1; off < 1024; off <<= 1) {
        int t = (tid >= off) ? sd[tid - off] : 0;
        __syncthreads();
        sd[tid] += t;
        __syncthreads();
    }
    if (tid < nb) bsum[tid] = sd[tid] - v;
}

__global__ void scan_add(int* __restrict__ row_ptr, int* __restrict__ cursor,
                         const int* __restrict__ bsum, int n, int E) {
    int i = blockIdx.x * blockDim.x + threadIdx.x;
    if (i < n) {
        int r = row_ptr[i] + bsum[i >> 10];
        row_ptr[i] = r;
        cursor[i] = r;
    }
    if (i == n) row_ptr[n] = E;
}

__global__ void fill_kernel(const int* __restrict__ src, const int* __restrict__ dst,
                            int* __restrict__ cursor, int* __restrict__ csr_src, int E) {
    int e = blockIdx.x * blockDim.x + threadIdx.x;
    if (e < E) {
        int pos = atomicAdd(&cursor[dst[e]], 1);
        csr_src[pos] = src[e];
    }
}

// W[256][256] f32 (k-major) -> Wt[256][256] bf16 (n-major: Wt[n][k])
__global__ void wt_kernel(const float* __restrict__ W, u16* __restrict__ Wt) {
    int t = blockIdx.x * blockDim.x + threadIdx.x;   // 65536
    int k = t >> 8, nn = t & 255;
    Wt[((size_t)nn << 8) + k] = f2bf(W[t]);
}

// ---------------------------------------------------------------------------
// MFMA GEMM: g[M x 256] = bf16( dinv[row] * (A[M x 256] @ W) )
// A f32 (layer1, converted in staging) or bf16 (layer2). W given as Wt[n][k].
// 128x128 tile, 4 waves 2x2, K=256. B slice staged full-K once (67.6 KB LDS);
// A staged per 32-K tile (10 KB). Rows padded +8 bf16 -> uniform bank spread.
// mfma_f32_16x16x32_bf16 layouts: A(row=l&15, k=(l>>4)*8+j),
// B(col=l&15, k=(l>>4)*8+j), D(col=l&15, row=(l>>4)*4+r).
// ---------------------------------------------------------------------------
template<bool AF32>
__global__ __launch_bounds__(256, 2) void mfma_gemm(const void* __restrict__ Ap,
        const u16* __restrict__ Wt, const float* __restrict__ dinv,
        u16* __restrict__ g, int M) {
    __shared__ u16 Bs[128][264];    // [col][k] 67584 B
    __shared__ u16 As[128][40];     // [row][k-tile] 10240 B
    const int tid = threadIdx.x;
    const int row0 = blockIdx.x * 128;
    const int col0 = blockIdx.y * 128;

    {   // stage B slice: Wt rows [col0, col0+128), all 256 k
        const int col = tid >> 1;
        const int bhalf = tid & 1;
        const u16* src = Wt + (((size_t)(col0 + col)) << 8) + bhalf * 128;
#pragma unroll
        for (int q = 0; q < 16; q++)
            *(us8*)&Bs[col][bhalf * 128 + q * 8] = *(const us8*)(src + q * 8);
    }

    const int lane = tid & 63;
    const int w = tid >> 6;
    const int wr = w >> 1, wc = w & 1;
    const int l15 = lane & 15, kg = lane >> 4;

    f32x4 acc[4][4];
#pragma unroll
    for (int mi = 0; mi < 4; mi++)
#pragma unroll
        for (int ni = 0; ni < 4; ni++)
            acc[mi][ni] = (f32x4){0.f, 0.f, 0.f, 0.f};

    const int srow = tid >> 1;
    const int shalf = tid & 1;
    const int grow = row0 + srow;

    for (int k0 = 0; k0 < 256; k0 += 32) {
        if (AF32) {
            const float* src = (const float*)Ap + ((size_t)grow << 8) + k0 + shalf * 16;
            float4 v[4];
#pragma unroll
            for (int q = 0; q < 4; q++)
                v[q] = (grow < M) ? *(const float4*)(src + q * 4)
                                  : make_float4(0.f, 0.f, 0.f, 0.f);
            u16 tmp[16];
#pragma unroll
            for (int q = 0; q < 4; q++) {
                tmp[q * 4 + 0] = f2bf(v[q].x); tmp[q * 4 + 1] = f2bf(v[q].y);
                tmp[q * 4 + 2] = f2bf(v[q].z); tmp[q * 4 + 3] = f2bf(v[q].w);
            }
            *(us8*)&As[srow][shalf * 16]     = *(us8*)&tmp[0];
            *(us8*)&As[srow][shalf * 16 + 8] = *(us8*)&tmp[8];
        } else {
            const u16* src = (const u16*)Ap + ((size_t)grow << 8) + k0 + shalf * 16;
            us8 z = {0, 0, 0, 0, 0, 0, 0, 0};
            us8 a0 = (grow < M) ? *(const us8*)src       : z;
            us8 a1 = (grow < M) ? *(const us8*)(src + 8) : z;
            *(us8*)&As[srow][shalf * 16]     = a0;
            *(us8*)&As[srow][shalf * 16 + 8] = a1;
        }
        __syncthreads();
        bf16x8 af[4], bfv[4];
#pragma unroll
        for (int mi = 0; mi < 4; mi++)
            af[mi] = *(const bf16x8*)&As[wr * 64 + mi * 16 + l15][kg * 8];
#pragma unroll
        for (int ni = 0; ni < 4; ni++)
            bfv[ni] = *(const bf16x8*)&Bs[wc * 64 + ni * 16 + l15][k0 + kg * 8];
#pragma unroll
        for (int mi = 0; mi < 4; mi++)
#pragma unroll
            for (int ni = 0; ni < 4; ni++)
                acc[mi][ni] = __builtin_amdgcn_mfma_f32_16x16x32_bf16(
                    af[mi], bfv[ni], acc[mi][ni], 0, 0, 0);
        __syncthreads();
    }

#pragma unroll
    for (int mi = 0; mi < 4; mi++) {
#pragma unroll
        for (int r = 0; r < 4; r++) {
            int gr = row0 + wr * 64 + mi * 16 + kg * 4 + r;
            if (gr < M) {
                float s = dinv[gr];
                u16* dstp = g + ((size_t)gr << 8) + col0 + wc * 64 + l15;
#pragma unroll
                for (int ni = 0; ni < 4; ni++)
                    dstp[ni * 16] = f2bf(acc[mi][ni][r] * s);
            }
        }
    }
}

// ---------------------------------------------------------------------------
// Aggregation: one wave per node, lane = 4 cols (ushort4 bf16 gather).
// f32 accumulate; epilogue scale by dinv, +bias, optional relu;
// output f32 (final) or bf16 (feeds GEMM2).
// ---------------------------------------------------------------------------
template<bool OUT16>
__global__ __launch_bounds__(256) void agg_kernel(const u16* __restrict__ g,
        const int* __restrict__ csr_src, const int* __restrict__ row_ptr,
        const float* __restrict__ dinv, const float* __restrict__ bias,
        void* __restrict__ outp, int n, int do_relu) {
    int wid = threadIdx.x >> 6;
    int lane = threadIdx.x & 63;
    int node = blockIdx.x * 4 + wid;
    if (node >= n) return;
    int jb = row_ptr[node], je = row_ptr[node + 1];
    const size_t co = (size_t)(lane * 4);
    float4 a0 = make_float4(0.f, 0.f, 0.f, 0.f);
    float4 a1 = make_float4(0.f, 0.f, 0.f, 0.f);
    int j = jb;
    for (; j + 8 <= je; j += 8) {
        int s0 = csr_src[j + 0], s1 = csr_src[j + 1];
        int s2 = csr_src[j + 2], s3 = csr_src[j + 3];
        int s4 = csr_src[j + 4], s5 = csr_src[j + 5];
        int s6 = csr_src[j + 6], s7 = csr_src[j + 7];
        ushort4 v0 = *(const ushort4*)(g + ((size_t)s0 << 8) + co);
        ushort4 v1 = *(const ushort4*)(g + ((size_t)s1 << 8) + co);
        ushort4 v2 = *(const ushort4*)(g + ((size_t)s2 << 8) + co);
        ushort4 v3 = *(const ushort4*)(g + ((size_t)s3 << 8) + co);
        ushort4 v4 = *(const ushort4*)(g + ((size_t)s4 << 8) + co);
        ushort4 v5 = *(const ushort4*)(g + ((size_t)s5 << 8) + co);
        ushort4 v6 = *(const ushort4*)(g + ((size_t)s6 << 8) + co);
        ushort4 v7 = *(const ushort4*)(g + ((size_t)s7 << 8) + co);
        a0.x += bf2f(v0.x); a0.y += bf2f(v0.y); a0.z += bf2f(v0.z); a0.w += bf2f(v0.w);
        a1.x += bf2f(v1.x); a1.y += bf2f(v1.y); a1.z += bf2f(v1.z); a1.w += bf2f(v1.w);
        a0.x += bf2f(v2.x); a0.y += bf2f(v2.y); a0.z += bf2f(v2.z); a0.w += bf2f(v2.w);
        a1.x += bf2f(v3.x); a1.y += bf2f(v3.y); a1.z += bf2f(v3.z); a1.w += bf2f(v3.w);
        a0.x += bf2f(v4.x); a0.y += bf2f(v4.y); a0.z += bf2f(v4.z); a0.w += bf2f(v4.w);
        a1.x += bf2f(v5.x); a1.y += bf2f(v5.y); a1.z += bf2f(v5.z); a1.w += bf2f(v5.w);
        a0.x += bf2f(v6.x); a0.y += bf2f(v6.y); a0.z += bf2f(v6.z); a0.w += bf2f(v6.w);
        a1.x += bf2f(v7.x); a1.y += bf2f(v7.y); a1.z += bf2f(v7.z); a1.w += bf2f(v7.w);
    }
    for (; j < je; ++j) {
        int s = csr_src[j];
        ushort4 v = *(const ushort4*)(g + ((size_t)s << 8) + co);
        a0.x += bf2f(v.x); a0.y += bf2f(v.y); a0.z += bf2f(v.z); a0.w += bf2f(v.w);
    }
    ushort4 gd = *(const ushort4*)(g + ((size_t)node << 8) + co);
    float dn = dinv[node];
    float4 bv = *(const float4*)(bias + co);
    float4 o;
    o.x = (a0.x + a1.x + bf2f(gd.x)) * dn + bv.x;
    o.y = (a0.y + a1.y + bf2f(gd.y)) * dn + bv.y;
    o.z = (a0.z + a1.z + bf2f(gd.z)) * dn + bv.z;
    o.w = (a0.w + a1.w + bf2f(gd.w)) * dn + bv.w;
    if (do_relu) {
        o.x = fmaxf(o.x, 0.f); o.y = fmaxf(o.y, 0.f);
        o.z = fmaxf(o.z, 0.f); o.w = fmaxf(o.w, 0.f);
    }
    if (OUT16) {
        us4 ov = { f2bf(o.x), f2bf(o.y), f2bf(o.z), f2bf(o.w) };
        *(us4*)((u16*)outp + ((size_t)node << 8) + co) = ov;
    } else {
        *(float4*)((float*)outp + ((size_t)node << 8) + co) = o;
    }
}

extern "C" void kernel_launch(void* const* d_in, const int* in_sizes, int n_in,
                              void* d_out, int out_size, void* d_ws, size_t ws_size,
                              hipStream_t stream) {
    // inputs: 0 gene_ind_vec (unused), 1 edge_index, 2 embedding, 3 W1, 4 b1, 5 W2, 6 b2
    const int*   edge_index = (const int*)d_in[1];
    const float* embedding  = (const float*)d_in[2];
    const float* W1 = (const float*)d_in[3];
    const float* b1 = (const float*)d_in[4];
    const float* W2 = (const float*)d_in[5];
    const float* b2 = (const float*)d_in[6];
    float* out = (float*)d_out;

    const int E = in_sizes[1] / 2;
    const int n = in_sizes[2] / 256;
    const int* src = edge_index;
    const int* dst = edge_index + E;

    char* ws = (char*)d_ws;
    int* cnt = (int*)ws;        ws += (size_t)n * 4;      // reused as cursor
    int* row_ptr = (int*)ws;    ws += ((size_t)n + 1) * 4;
    float* dinv = (float*)ws;   ws += (size_t)n * 4;
    int* bsum = (int*)ws;       ws += 1024 * 4;
    int* csr_src = (int*)ws;    ws += (size_t)E * 4;
    u16* Wt1 = (u16*)ws;        ws += 65536 * 2;
    u16* Wt2 = (u16*)ws;        ws += 65536 * 2;
    ws = (char*)(((uintptr_t)ws + 127) & ~(uintptr_t)127);
    u16* g = (u16*)ws;          // n*256 bf16 (25.6 MB)
    u16* x1 = (u16*)d_out;      // bf16 x1 scratch lives in d_out; consumed by
                                // gemm2 before final agg overwrites d_out (stream-ordered)

    const int tb = 256;
    const int nchunks = (n + 1023) / 1024;
    hipMemsetAsync(cnt, 0, (size_t)n * 4, stream);
    count_kernel<<<(E + tb - 1) / tb, tb, 0, stream>>>(dst, cnt, E);
    dinv_kernel<<<(n + tb - 1) / tb, tb, 0, stream>>>(cnt, dinv, n);
    scan_block<<<nchunks, 1024, 0, stream>>>(cnt, row_ptr, bsum, n);
    scan_bsum<<<1, 1024, 0, stream>>>(bsum, nchunks);
    scan_add<<<(n + tb) / tb, tb, 0, stream>>>(row_ptr, cnt, bsum, n, E);
    fill_kernel<<<(E + tb - 1) / tb, tb, 0, stream>>>(src, dst, cnt, csr_src, E);
    wt_kernel<<<256, 256, 0, stream>>>(W1, Wt1);
    wt_kernel<<<256, 256, 0, stream>>>(W2, Wt2);

    dim3 gg((n + 127) / 128, 2);
    // layer 1: g1 = bf16(dinv*(X@W1)); x1 = bf16(relu(dinv*(agg+self)+b1))
    mfma_gemm<true><<<gg, 256, 0, stream>>>(embedding, Wt1, dinv, g, n);
    agg_kernel<true><<<(n + 3) / 4, 256, 0, stream>>>(g, csr_src, row_ptr, dinv, b1, x1, n, 1);
    // layer 2: g2 = bf16(dinv*(x1@W2)); out = dinv*(agg+self)+b2 (f32)
    mfma_gemm<false><<<gg, 256, 0, stream>>>(x1, Wt2, dinv, g, n);
    agg_kernel<false><<<(n + 3) / 4, 256, 0, stream>>>(g, csr_src, row_ptr, dinv, b2, out, n, 0);
}

// Round 5
// 263.664 us; speedup vs baseline: 2.7650x; 1.3180x over previous
//
#include <hip/hip_runtime.h>
#include <stdint.h>

// ---------------------------------------------------------------------------
// 2-layer GCN. g = (xW) row-scaled by dinv, stored BF16 (MFMA bf16 GEMM).
// out[d] = dinv[d] * (sum_{s in N(d)} g[s] + g[d]) + b, f32 accumulate.
// R5: bucketed CSR build (write-local) replaces count/scan/fill chain whose
// random 4B scatters caused 16x write amplification (67.5MB WRITE for 4MB).
// ---------------------------------------------------------------------------

typedef unsigned short u16;
typedef __bf16 bf16x8 __attribute__((ext_vector_type(8)));
typedef float f32x4 __attribute__((ext_vector_type(4)));
typedef unsigned short us8 __attribute__((ext_vector_type(8)));
typedef unsigned short us4 __attribute__((ext_vector_type(4)));

#define BSHIFT 8                  // bucket = dst >> 8 (256 nodes/bucket)
#define BSTRIDE 6144              // record slots per bucket (mean 5102, +14 sigma)
#define EPT 8                     // edges per thread in scatter
#define TILE (256 * EPT)

__device__ __forceinline__ float bf2f(u16 u) {
    union { unsigned i; float f; } c;
    c.i = ((unsigned)u) << 16;
    return c.f;
}
__device__ __forceinline__ u16 f2bf(float f) {
    union { float f; unsigned i; } c;
    c.f = f;
    unsigned i = c.i;
    return (u16)((i + 0x7FFF + ((i >> 16) & 1)) >> 16);   // RNE
}

// ---------------------------------------------------------------------------
// CSR build, pass 1: tile-sorted scatter of (dst,src) records into bucket
// segments. Per-tile LDS histogram -> one global cursor atomic per
// (tile,bucket) -> records land as contiguous runs (write-local).
// ---------------------------------------------------------------------------
__global__ __launch_bounds__(256) void scatter_kernel(const int* __restrict__ src,
        const int* __restrict__ dst, int* __restrict__ bcursor,
        int2* __restrict__ rec, int E) {
    __shared__ int cnt[256], lcur[256], gbase[256];
    const int t = threadIdx.x;
    const int base = blockIdx.x * TILE;
    cnt[t] = 0;
    __syncthreads();
    int d[EPT], s[EPT], b[EPT];
#pragma unroll
    for (int k = 0; k < EPT; k++) {
        int e = base + t + k * 256;
        if (e < E) {
            d[k] = dst[e];
            s[k] = src[e];
            b[k] = d[k] >> BSHIFT;
            atomicAdd(&cnt[b[k]], 1);
        } else b[k] = -1;
    }
    __syncthreads();
    int c = cnt[t];
    if (c > 0) gbase[t] = atomicAdd(&bcursor[t], c);
    lcur[t] = 0;
    __syncthreads();
#pragma unroll
    for (int k = 0; k < EPT; k++) {
        if (b[k] >= 0) {
            int r = atomicAdd(&lcur[b[k]], 1);
            rec[(size_t)b[k] * BSTRIDE + gbase[b[k]] + r] = make_int2(d[k], s[k]);
        }
    }
}

// pass 2: exclusive scan of bucket counts (one block) -> bbase; row_ptr[n]=E
__global__ __launch_bounds__(256) void bucket_scan(const int* __restrict__ bcursor,
        int* __restrict__ bbase, int* __restrict__ row_ptr, int NB, int n, int E) {
    __shared__ int sc[256];
    int t = threadIdx.x;
    int v = (t < NB) ? bcursor[t] : 0;
    sc[t] = v;
    __syncthreads();
    for (int off = 1; off < 256; off <<= 1) {
        int u = (t >= off) ? sc[t - off] : 0;
        __syncthreads();
        sc[t] += u;
        __syncthreads();
    }
    if (t < NB) bbase[t] = sc[t] - v;      // exclusive
    if (t == 0) { bbase[NB] = E; row_ptr[n] = E; }
}

// pass 3: per-bucket (one WG) local count + scan + scatter into csr_src.
// Also emits row_ptr and dinv for the bucket's nodes.
__global__ __launch_bounds__(256) void bucket_build(const int2* __restrict__ rec,
        const int* __restrict__ bcursor, const int* __restrict__ bbase,
        int* __restrict__ row_ptr, float* __restrict__ dinv,
        int* __restrict__ csr_src, int n) {
    __shared__ int cnt[256], loff[256], sc[256];
    const int b = blockIdx.x;
    const int t = threadIdx.x;
    const int m = bcursor[b];               // records in this bucket
    const int base = bbase[b];
    const int2* r = rec + (size_t)b * BSTRIDE;
    cnt[t] = 0;
    __syncthreads();
    for (int i = t; i < m; i += 256)
        atomicAdd(&cnt[r[i].x & 255], 1);
    __syncthreads();
    int c = cnt[t];
    sc[t] = c;
    __syncthreads();
    for (int off = 1; off < 256; off <<= 1) {
        int u = (t >= off) ? sc[t - off] : 0;
        __syncthreads();
        sc[t] += u;
        __syncthreads();
    }
    loff[t] = sc[t] - c;                    // exclusive
    int node = (b << BSHIFT) + t;
    if (node < n) {
        row_ptr[node] = base + loff[t];
        dinv[node] = 1.0f / sqrtf((float)c + 1.0f);
    }
    __syncthreads();
    // reuse sc as live cursors
    sc[t] = loff[t];
    __syncthreads();
    for (int i = t; i < m; i += 256) {
        int2 e = r[i];
        int idx = atomicAdd(&sc[e.x & 255], 1);
        csr_src[base + idx] = e.y;
    }
}

// W[256][256] f32 (k-major) -> Wt[256][256] bf16 (n-major: Wt[n][k])
__global__ void wt_kernel(const float* __restrict__ W, u16* __restrict__ Wt) {
    int t = blockIdx.x * blockDim.x + threadIdx.x;   // 65536
    int k = t >> 8, nn = t & 255;
    Wt[((size_t)nn << 8) + k] = f2bf(W[t]);
}

// ---------------------------------------------------------------------------
// MFMA GEMM: g[M x 256] = bf16( dinv[row] * (A[M x 256] @ W) )
// A f32 (layer1, converted in staging) or bf16 (layer2). W given as Wt[n][k].
// 128x128 tile, 4 waves 2x2, K=256. B slice staged full-K once (67.6 KB LDS);
// A staged per 32-K tile (10 KB).
// ---------------------------------------------------------------------------
template<bool AF32>
__global__ __launch_bounds__(256, 2) void mfma_gemm(const void* __restrict__ Ap,
        const u16* __restrict__ Wt, const float* __restrict__ dinv,
        u16* __restrict__ g, int M) {
    __shared__ u16 Bs[128][264];    // [col][k] 67584 B
    __shared__ u16 As[128][40];     // [row][k-tile] 10240 B
    const int tid = threadIdx.x;
    const int row0 = blockIdx.x * 128;
    const int col0 = blockIdx.y * 128;

    {   // stage B slice: Wt rows [col0, col0+128), all 256 k
        const int col = tid >> 1;
        const int bhalf = tid & 1;
        const u16* srcp = Wt + (((size_t)(col0 + col)) << 8) + bhalf * 128;
#pragma unroll
        for (int q = 0; q < 16; q++)
            *(us8*)&Bs[col][bhalf * 128 + q * 8] = *(const us8*)(srcp + q * 8);
    }

    const int lane = tid & 63;
    const int w = tid >> 6;
    const int wr = w >> 1, wc = w & 1;
    const int l15 = lane & 15, kg = lane >> 4;

    f32x4 acc[4][4];
#pragma unroll
    for (int mi = 0; mi < 4; mi++)
#pragma unroll
        for (int ni = 0; ni < 4; ni++)
            acc[mi][ni] = (f32x4){0.f, 0.f, 0.f, 0.f};

    const int srow = tid >> 1;
    const int shalf = tid & 1;
    const int grow = row0 + srow;

    for (int k0 = 0; k0 < 256; k0 += 32) {
        if (AF32) {
            const float* srcp = (const float*)Ap + ((size_t)grow << 8) + k0 + shalf * 16;
            float4 v[4];
#pragma unroll
            for (int q = 0; q < 4; q++)
                v[q] = (grow < M) ? *(const float4*)(srcp + q * 4)
                                  : make_float4(0.f, 0.f, 0.f, 0.f);
            u16 tmp[16];
#pragma unroll
            for (int q = 0; q < 4; q++) {
                tmp[q * 4 + 0] = f2bf(v[q].x); tmp[q * 4 + 1] = f2bf(v[q].y);
                tmp[q * 4 + 2] = f2bf(v[q].z); tmp[q * 4 + 3] = f2bf(v[q].w);
            }
            *(us8*)&As[srow][shalf * 16]     = *(us8*)&tmp[0];
            *(us8*)&As[srow][shalf * 16 + 8] = *(us8*)&tmp[8];
        } else {
            const u16* srcp = (const u16*)Ap + ((size_t)grow << 8) + k0 + shalf * 16;
            us8 z = {0, 0, 0, 0, 0, 0, 0, 0};
            us8 a0 = (grow < M) ? *(const us8*)srcp       : z;
            us8 a1 = (grow < M) ? *(const us8*)(srcp + 8) : z;
            *(us8*)&As[srow][shalf * 16]     = a0;
            *(us8*)&As[srow][shalf * 16 + 8] = a1;
        }
        __syncthreads();
        bf16x8 af[4], bfv[4];
#pragma unroll
        for (int mi = 0; mi < 4; mi++)
            af[mi] = *(const bf16x8*)&As[wr * 64 + mi * 16 + l15][kg * 8];
#pragma unroll
        for (int ni = 0; ni < 4; ni++)
            bfv[ni] = *(const bf16x8*)&Bs[wc * 64 + ni * 16 + l15][k0 + kg * 8];
#pragma unroll
        for (int mi = 0; mi < 4; mi++)
#pragma unroll
            for (int ni = 0; ni < 4; ni++)
                acc[mi][ni] = __builtin_amdgcn_mfma_f32_16x16x32_bf16(
                    af[mi], bfv[ni], acc[mi][ni], 0, 0, 0);
        __syncthreads();
    }

#pragma unroll
    for (int mi = 0; mi < 4; mi++) {
#pragma unroll
        for (int r = 0; r < 4; r++) {
            int gr = row0 + wr * 64 + mi * 16 + kg * 4 + r;
            if (gr < M) {
                float s = dinv[gr];
                u16* dstp = g + ((size_t)gr << 8) + col0 + wc * 64 + l15;
#pragma unroll
                for (int ni = 0; ni < 4; ni++)
                    dstp[ni * 16] = f2bf(acc[mi][ni][r] * s);
            }
        }
    }
}

// ---------------------------------------------------------------------------
// Aggregation: one wave per node, lane = 4 cols (ushort4 bf16 gather).
// f32 accumulate; epilogue scale by dinv, +bias, optional relu;
// output f32 (final) or bf16 (feeds GEMM2).
// ---------------------------------------------------------------------------
template<bool OUT16>
__global__ __launch_bounds__(256) void agg_kernel(const u16* __restrict__ g,
        const int* __restrict__ csr_src, const int* __restrict__ row_ptr,
        const float* __restrict__ dinv, const float* __restrict__ bias,
        void* __restrict__ outp, int n, int do_relu) {
    int wid = threadIdx.x >> 6;
    int lane = threadIdx.x & 63;
    int node = blockIdx.x * 4 + wid;
    if (node >= n) return;
    int jb = row_ptr[node], je = row_ptr[node + 1];
    const size_t co = (size_t)(lane * 4);
    float4 a0 = make_float4(0.f, 0.f, 0.f, 0.f);
    float4 a1 = make_float4(0.f, 0.f, 0.f, 0.f);
    int j = jb;
    for (; j + 8 <= je; j += 8) {
        int s0 = csr_src[j + 0], s1 = csr_src[j + 1];
        int s2 = csr_src[j + 2], s3 = csr_src[j + 3];
        int s4 = csr_src[j + 4], s5 = csr_src[j + 5];
        int s6 = csr_src[j + 6], s7 = csr_src[j + 7];
        ushort4 v0 = *(const ushort4*)(g + ((size_t)s0 << 8) + co);
        ushort4 v1 = *(const ushort4*)(g + ((size_t)s1 << 8) + co);
        ushort4 v2 = *(const ushort4*)(g + ((size_t)s2 << 8) + co);
        ushort4 v3 = *(const ushort4*)(g + ((size_t)s3 << 8) + co);
        ushort4 v4 = *(const ushort4*)(g + ((size_t)s4 << 8) + co);
        ushort4 v5 = *(const ushort4*)(g + ((size_t)s5 << 8) + co);
        ushort4 v6 = *(const ushort4*)(g + ((size_t)s6 << 8) + co);
        ushort4 v7 = *(const ushort4*)(g + ((size_t)s7 << 8) + co);
        a0.x += bf2f(v0.x); a0.y += bf2f(v0.y); a0.z += bf2f(v0.z); a0.w += bf2f(v0.w);
        a1.x += bf2f(v1.x); a1.y += bf2f(v1.y); a1.z += bf2f(v1.z); a1.w += bf2f(v1.w);
        a0.x += bf2f(v2.x); a0.y += bf2f(v2.y); a0.z += bf2f(v2.z); a0.w += bf2f(v2.w);
        a1.x += bf2f(v3.x); a1.y += bf2f(v3.y); a1.z += bf2f(v3.z); a1.w += bf2f(v3.w);
        a0.x += bf2f(v4.x); a0.y += bf2f(v4.y); a0.z += bf2f(v4.z); a0.w += bf2f(v4.w);
        a1.x += bf2f(v5.x); a1.y += bf2f(v5.y); a1.z += bf2f(v5.z); a1.w += bf2f(v5.w);
        a0.x += bf2f(v6.x); a0.y += bf2f(v6.y); a0.z += bf2f(v6.z); a0.w += bf2f(v6.w);
        a1.x += bf2f(v7.x); a1.y += bf2f(v7.y); a1.z += bf2f(v7.z); a1.w += bf2f(v7.w);
    }
    for (; j < je; ++j) {
        int s = csr_src[j];
        ushort4 v = *(const ushort4*)(g + ((size_t)s << 8) + co);
        a0.x += bf2f(v.x); a0.y += bf2f(v.y); a0.z += bf2f(v.z); a0.w += bf2f(v.w);
    }
    ushort4 gd = *(const ushort4*)(g + ((size_t)node << 8) + co);
    float dn = dinv[node];
    float4 bv = *(const float4*)(bias + co);
    float4 o;
    o.x = (a0.x + a1.x + bf2f(gd.x)) * dn + bv.x;
    o.y = (a0.y + a1.y + bf2f(gd.y)) * dn + bv.y;
    o.z = (a0.z + a1.z + bf2f(gd.z)) * dn + bv.z;
    o.w = (a0.w + a1.w + bf2f(gd.w)) * dn + bv.w;
    if (do_relu) {
        o.x = fmaxf(o.x, 0.f); o.y = fmaxf(o.y, 0.f);
        o.z = fmaxf(o.z, 0.f); o.w = fmaxf(o.w, 0.f);
    }
    if (OUT16) {
        us4 ov = { f2bf(o.x), f2bf(o.y), f2bf(o.z), f2bf(o.w) };
        *(us4*)((u16*)outp + ((size_t)node << 8) + co) = ov;
    } else {
        *(float4*)((float*)outp + ((size_t)node << 8) + co) = o;
    }
}

extern "C" void kernel_launch(void* const* d_in, const int* in_sizes, int n_in,
                              void* d_out, int out_size, void* d_ws, size_t ws_size,
                              hipStream_t stream) {
    // inputs: 0 gene_ind_vec (unused), 1 edge_index, 2 embedding, 3 W1, 4 b1, 5 W2, 6 b2
    const int*   edge_index = (const int*)d_in[1];
    const float* embedding  = (const float*)d_in[2];
    const float* W1 = (const float*)d_in[3];
    const float* b1 = (const float*)d_in[4];
    const float* W2 = (const float*)d_in[5];
    const float* b2 = (const float*)d_in[6];
    float* out = (float*)d_out;

    const int E = in_sizes[1] / 2;
    const int n = in_sizes[2] / 256;
    const int* src = edge_index;
    const int* dst = edge_index + E;
    const int NB = (n + 255) >> BSHIFT;     // buckets

    char* ws = (char*)d_ws;
    int* row_ptr = (int*)ws;    ws += ((size_t)n + 1) * 4;
    float* dinv = (float*)ws;   ws += (size_t)n * 4;
    int* bcursor = (int*)ws;    ws += 256 * 4;
    int* bbase = (int*)ws;      ws += 257 * 4;
    int* csr_src = (int*)ws;    ws += (size_t)E * 4;
    u16* Wt1 = (u16*)ws;        ws += 65536 * 2;
    u16* Wt2 = (u16*)ws;        ws += 65536 * 2;
    ws = (char*)(((uintptr_t)ws + 127) & ~(uintptr_t)127);
    int2* rec = (int2*)ws;      ws += (size_t)NB * BSTRIDE * 8;
    ws = (char*)(((uintptr_t)ws + 127) & ~(uintptr_t)127);
    u16* g = (u16*)ws;          // n*256 bf16 (25.6 MB)
    u16* x1 = (u16*)d_out;      // bf16 x1 scratch in d_out; consumed by gemm2
                                // before final agg overwrites d_out

    hipMemsetAsync(bcursor, 0, 256 * 4, stream);
    scatter_kernel<<<(E + TILE - 1) / TILE, 256, 0, stream>>>(src, dst, bcursor, rec, E);
    bucket_scan<<<1, 256, 0, stream>>>(bcursor, bbase, row_ptr, NB, n, E);
    bucket_build<<<NB, 256, 0, stream>>>(rec, bcursor, bbase, row_ptr, dinv, csr_src, n);
    wt_kernel<<<256, 256, 0, stream>>>(W1, Wt1);
    wt_kernel<<<256, 256, 0, stream>>>(W2, Wt2);

    dim3 gg((n + 127) / 128, 2);
    // layer 1: g1 = bf16(dinv*(X@W1)); x1 = bf16(relu(dinv*(agg+self)+b1))
    mfma_gemm<true><<<gg, 256, 0, stream>>>(embedding, Wt1, dinv, g, n);
    agg_kernel<true><<<(n + 3) / 4, 256, 0, stream>>>(g, csr_src, row_ptr, dinv, b1, x1, n, 1);
    // layer 2: g2 = bf16(dinv*(x1@W2)); out = dinv*(agg+self)+b2 (f32)
    mfma_gemm<false><<<gg, 256, 0, stream>>>(x1, Wt2, dinv, g, n);
    agg_kernel<false><<<(n + 3) / 4, 256, 0, stream>>>(g, csr_src, row_ptr, dinv, b2, out, n, 0);
}